// Round 7
// baseline (2908.486 us; speedup 1.0000x reference)
//
#include <hip/hip_runtime.h>
#include <math.h>

#define NN 2048
#define KK 20
#define EPSF 1e-5f

__device__ __forceinline__ float lrelu(float v){ return v >= 0.f ? v : 0.2f*v; }

// Sorted (descending, ties by ascending id) top-20 insert. Caller guards d > v[19].
__device__ __forceinline__ void topk20_insert(float d, int idc, float (&v)[KK], int (&id)[KK]){
#pragma unroll
  for (int j = KK-1; j >= 1; --j){
    bool cjm1 = d > v[j-1];
    bool cj   = d > v[j];
    float nv = cjm1 ? v[j-1] : (cj ? d   : v[j]);
    int   ni = cjm1 ? id[j-1] : (cj ? idc : id[j]);
    v[j] = nv; id[j] = ni;
  }
  if (d > v[0]) { v[0] = d; id[0] = idc; }
}

// ---------- stage 1 prep: sq norms + y1 = Wa1*x, t1 = (Wb1-Wa1)*x ----------
__global__ void k_prep1(const float* __restrict__ x, const float* __restrict__ W1,
                        float* __restrict__ Y, float* __restrict__ T, float* __restrict__ SQ){
  __shared__ float wa[64][3], wd[64][3];
  int t = threadIdx.x;
  if (t < 64){
#pragma unroll
    for (int c=0;c<3;c++){
      float a = W1[t*6+c], b2 = W1[t*6+3+c];
      wa[t][c] = a; wd[t][c] = b2 - a;
    }
  }
  __syncthreads();
  int gid = blockIdx.x*256 + t;
  int b = gid >> 11, n = gid & (NN-1);
  float px = x[gid*3+0], py = x[gid*3+1], pz = x[gid*3+2];
  SQ[gid] = px*px + py*py + pz*pz;
  float* yb = Y + ((size_t)b*128)*NN + n;
  float* tb = T + ((size_t)b*128)*NN + n;
#pragma unroll 8
  for (int o=0;o<64;o++){
    yb[(size_t)o*NN] = wa[o][0]*px + wa[o][1]*py + wa[o][2]*pz;
    tb[(size_t)o*NN] = wd[o][0]*px + wd[o][1]*py + wd[o][2]*pz;
  }
}

// ---------- KNN on raw xyz, candidate-split halves; each LANE writes its own partial ----------
// LDS = 2 KB (cd only). No in-kernel merge.
__global__ __launch_bounds__(256,4) void k_knn3_part(const float* __restrict__ x, const float* __restrict__ SQ,
                                                     float* __restrict__ PV, unsigned short* __restrict__ PI){
  __shared__ __align__(16) float cd[128*4];
  int t = threadIdx.x;
  int half = blockIdx.x & 1, nb = blockIdx.x >> 1;
  int b = blockIdx.y;
  int n_base = nb * 32;
  int cbase = half * 1024;
  int ql = t & 31, sp = t >> 5;
  int n = n_base + ql;
  int gq = b*NN + n;
  float qx = x[gq*3], qy = x[gq*3+1], qz = x[gq*3+2];
  float qs = SQ[gq];
  float v[KK]; int id[KK];
#pragma unroll
  for (int i=0;i<KK;i++){ v[i] = -INFINITY; id[i] = 0; }
  int mlo = sp * 16;
  for (int tile=0; tile<8; ++tile){
    int m0 = cbase + tile * 128;
    __syncthreads();
#pragma unroll
    for (int i=0;i<2;i++){
      int f2 = t + i*256;
      int m = f2 >> 2, ch = f2 & 3;
      int gm = b*NN + m0 + m;
      cd[f2] = (ch < 3) ? x[gm*3 + ch] : SQ[gm];
    }
    __syncthreads();
    for (int j=mlo; j<mlo+16; ++j){
      float4 c4 = *(const float4*)&cd[j*4];
      float d = 2.f*(qx*c4.x + qy*c4.y + qz*c4.z) - qs - c4.w;
      if (d > v[KK-1]) topk20_insert(d, m0 + j, v, id);
    }
  }
  // direct per-lane partial write: list id = half*8 + sp
  size_t base = ((size_t)b*16 + half*8 + sp)*KK;
#pragma unroll
  for (int r=0;r<KK;r++){
    PV[(base + r)*NN + n] = v[r];
    PI[(base + r)*NN + n] = (unsigned short)id[r];
  }
}

// ---------- squared norms of a 64-channel feature region ----------
__global__ void k_sqnorm(const float* __restrict__ X, float* __restrict__ SQ){
  int gid = blockIdx.x*256 + threadIdx.x;
  int b = gid >> 11, n = gid & (NN-1);
  const float* xb = X + (size_t)b*256*NN;
  float s = 0.f;
#pragma unroll
  for (int c=0;c<64;c++){ float vv = xb[(size_t)c*NN + n]; s += vv*vv; }
  SQ[gid] = s;
}

// ---------- KNN on 64-ch features, candidate-split halves, 64-row tiles ----------
// LDS = 64*68*4 + 64*4 = 17,664 B -> >=4 blocks/CU. Per-lane direct partial write.
__global__ __launch_bounds__(256,4) void k_knn64_part(const float* __restrict__ X, const float* __restrict__ SQ,
                                                      float* __restrict__ PV, unsigned short* __restrict__ PI){
  __shared__ __align__(16) float cd[64*68];
  __shared__ float cs_[64];
  int t = threadIdx.x;
  int half = blockIdx.x & 1, nb = blockIdx.x >> 1;
  int b = blockIdx.y;
  int n_base = nb * 32;
  int cbase = half * 1024;
  int ql = t & 31, sp = t >> 5;
  int n = n_base + ql;
  const float* xb = X + (size_t)b*256*NN;
  float q[64];
#pragma unroll
  for (int c=0;c<64;c++) q[c] = xb[(size_t)c*NN + n];
  float qs = SQ[b*NN + n];
  float v[KK]; int id[KK];
#pragma unroll
  for (int i=0;i<KK;i++){ v[i]=-INFINITY; id[i]=0; }
  int jlo = sp * 8;
  for (int tile=0; tile<16; ++tile){
    int m0 = cbase + tile*64;
    __syncthreads();
#pragma unroll
    for (int i=0;i<16;i++){
      int flat = i*256 + t;
      int c = flat >> 6, m = flat & 63;
      cd[m*68 + c] = xb[(size_t)c*NN + m0 + m];
    }
    if (t < 64) cs_[t] = SQ[b*NN + m0 + t];
    __syncthreads();
    for (int j=jlo; j<jlo+8; ++j){
      const float* crow = cd + j*68;
      float d = 0.f;
#pragma unroll
      for (int c=0;c<64;c+=4){
        float4 c4 = *(const float4*)&crow[c];
        d += q[c]*c4.x + q[c+1]*c4.y + q[c+2]*c4.z + q[c+3]*c4.w;
      }
      d = 2.f*d - qs - cs_[j];
      if (d > v[KK-1]) topk20_insert(d, m0 + j, v, id);
    }
  }
  size_t base = ((size_t)b*16 + half*8 + sp)*KK;
#pragma unroll
  for (int r=0;r<KK;r++){
    PV[(base + r)*NN + n] = v[r];
    PI[(base + r)*NN + n] = (unsigned short)id[r];
  }
}

// ---------- exact 16-way merge of sorted partials (v desc, id asc) -> IDX ----------
__global__ void k_topk_merge16(const float* __restrict__ PV, const unsigned short* __restrict__ PI,
                               int* __restrict__ IDX){
  int gid = blockIdx.x*256 + threadIdx.x;   // B*NN
  int b = gid >> 11, n = gid & (NN-1);
  float hv[16]; int hi_[16]; int hp[16];
#pragma unroll
  for (int s=0;s<16;s++){
    hp[s] = 0;
    hv[s] = PV[(((size_t)b*16 + s)*KK)*NN + n];
    hi_[s] = (int)PI[(((size_t)b*16 + s)*KK)*NN + n];
  }
  for (int r=0;r<KK;r++){
    float bv = hv[0]; int bi = hi_[0]; int bs = 0;
#pragma unroll
    for (int s=1;s<16;s++){
      bool win = (hv[s] > bv) || ((hv[s] == bv) && (hi_[s] < bi));
      bv = win ? hv[s] : bv; bi = win ? hi_[s] : bi; bs = win ? s : bs;
    }
    IDX[((size_t)b*KK + r)*NN + n] = bi;
#pragma unroll
    for (int s=0;s<16;s++){
      if (s == bs){
        int np = hp[s] + 1; hp[s] = np;
        bool ok = np < KK;
        hv[s]  = ok ? PV[(((size_t)b*16 + s)*KK + np)*NN + n] : -INFINITY;
        hi_[s] = ok ? (int)PI[(((size_t)b*16 + s)*KK + np)*NN + n] : 0x7FFFFFFF;
      }
    }
  }
}

// ---------- gather-max + BN + lrelu; idx loaded once per point, reused for 16 channels ----------
__global__ __launch_bounds__(256) void k_edge_apply(const float* __restrict__ Y, const float* __restrict__ T,
                             const int* __restrict__ IDX,
                             const float* __restrict__ g, const float* __restrict__ be,
                             const float* __restrict__ mu, const float* __restrict__ va,
                             float* __restrict__ OUT, int c_off){
  int t = threadIdx.x;
  int nl = t & 127, oh = t >> 7;
  int n = blockIdx.x*128 + nl;
  int b = blockIdx.z;
  int o0 = blockIdx.y*32 + oh*16;
  int idx[KK];
#pragma unroll
  for (int k2=0;k2<KK;k2++) idx[k2] = IDX[((size_t)b*KK + k2)*NN + n];
  for (int oo=0;oo<16;oo++){
    int o = o0 + oo;
    const float* yrow = Y + ((size_t)b*128 + o)*NN;
    float M = -INFINITY;
#pragma unroll
    for (int k2=0;k2<KK;k2++) M = fmaxf(M, yrow[idx[k2]]);
    float s = g[o] * rsqrtf(va[o] + EPSF);
    float val = s*(M + T[((size_t)b*128 + o)*NN + n] - mu[o]) + be[o];
    OUT[((size_t)b*256 + c_off + o)*NN + n] = lrelu(val);
  }
}

// ---------- y = Wa*X, t = (Wb-Wa)*X  (W is (O,128): [Wa | Wb]) ----------
template<int O>
__global__ __launch_bounds__(256) void k_yt_gemm(const float* __restrict__ X, const float* __restrict__ W,
                                                 float* __restrict__ Y, float* __restrict__ T){
  __shared__ __align__(16) float wa[O][64];
  __shared__ __align__(16) float wd[O][64];
  int t = threadIdx.x;
  for (int i=t; i<O*64; i+=256){
    int o = i >> 6, c = i & 63;
    float a = W[o*128 + c];
    wa[o][c] = a;
    wd[o][c] = W[o*128 + 64 + c] - a;
  }
  __syncthreads();
  int half = t >> 7, ln = t & 127;
  int gid = blockIdx.x*128 + ln;
  int b = gid >> 11, n = gid & (NN-1);
  const float* xb = X + (size_t)b*256*NN;
  float q[64];
#pragma unroll
  for (int c=0;c<64;c++) q[c] = xb[(size_t)c*NN + n];
  int o0 = half * (O/2);
  for (int o=o0; o<o0+O/2; ++o){
    float ay=0.f, at=0.f;
#pragma unroll
    for (int c=0;c<64;c+=4){
      float4 a4 = *(const float4*)&wa[o][c];
      float4 d4 = *(const float4*)&wd[o][c];
      ay += a4.x*q[c] + a4.y*q[c+1] + a4.z*q[c+2] + a4.w*q[c+3];
      at += d4.x*q[c] + d4.y*q[c+1] + d4.z*q[c+2] + d4.w*q[c+3];
    }
    Y[((size_t)b*128 + o)*NN + n] = ay;
    T[((size_t)b*128 + o)*NN + n] = at;
  }
}

// ---------- one-time W4 transpose: W4T[c][o] = W4[o][c] ----------
__global__ __launch_bounds__(256) void k_w4t(const float* __restrict__ W4, float* __restrict__ W4T){
  __shared__ float Tt[64][65];
  int t = threadIdx.x;
  int c0 = blockIdx.x * 64, o0 = blockIdx.y * 64;
#pragma unroll
  for (int p=0;p<16;p++){
    int f = p*256 + t;
    int i = f >> 6, j = f & 63;
    Tt[i][j] = W4[(size_t)(o0+i)*256 + c0 + j];
  }
  __syncthreads();
#pragma unroll
  for (int p=0;p<16;p++){
    int f = p*256 + t;
    int i = f >> 6, j = f & 63;
    W4T[(size_t)(c0+i)*1024 + o0 + j] = Tt[j][i];
  }
}

// ---------- W4 GEMM (128x128 tile, 8x8/thread) with on-the-fly partial max over n ----------
__global__ __launch_bounds__(256) void k_w4max(const float* __restrict__ CAT, const float* __restrict__ W4T,
                                               float* __restrict__ PART){
  __shared__ __align__(16) float wt[32][132];   // [c][o]
  __shared__ __align__(16) float ct[32][132];   // [c][n]
  int t = threadIdx.x;
  int io = t >> 4, in_ = t & 15;
  int nb = blockIdx.x * 128, ob = blockIdx.y * 128, b = blockIdx.z;
  const float* catb = CAT + (size_t)b*256*NN;
  float acc[8][8];
#pragma unroll
  for (int r=0;r<8;r++)
#pragma unroll
    for (int c=0;c<8;c++) acc[r][c]=0.f;
  for (int c0=0; c0<256; c0+=32){
    __syncthreads();
#pragma unroll
    for (int p=0;p<4;p++){
      int idx = p*256 + t;            // 1024 float4 = 32c x 128o
      int cc = idx >> 5, o4 = (idx & 31) * 4;
      *(float4*)&wt[cc][o4] = *(const float4*)&W4T[(size_t)(c0+cc)*1024 + ob + o4];
    }
#pragma unroll
    for (int p=0;p<4;p++){
      int idx = p*256 + t;
      int cc = idx >> 5, n4 = (idx & 31) * 4;
      *(float4*)&ct[cc][n4] = *(const float4*)&catb[(size_t)(c0+cc)*NN + nb + n4];
    }
    __syncthreads();
#pragma unroll 4
    for (int c=0;c<32;c++){
      float4 a0 = *(const float4*)&wt[c][io*8];
      float4 a1 = *(const float4*)&wt[c][io*8+4];
      float4 b0 = *(const float4*)&ct[c][in_*8];
      float4 b1 = *(const float4*)&ct[c][in_*8+4];
      float ar[8] = {a0.x,a0.y,a0.z,a0.w,a1.x,a1.y,a1.z,a1.w};
      float br[8] = {b0.x,b0.y,b0.z,b0.w,b1.x,b1.y,b1.z,b1.w};
#pragma unroll
      for (int r=0;r<8;r++)
#pragma unroll
        for (int s=0;s<8;s++) acc[r][s] += ar[r]*br[s];
    }
  }
#pragma unroll
  for (int r=0;r<8;r++){
    float m = acc[r][0];
#pragma unroll
    for (int s=1;s<8;s++) m = fmaxf(m, acc[r][s]);
    m = fmaxf(m, __shfl_xor(m, 1));
    m = fmaxf(m, __shfl_xor(m, 2));
    m = fmaxf(m, __shfl_xor(m, 4));
    m = fmaxf(m, __shfl_xor(m, 8));
    if (in_ == 0){
      int o = ob + io*8 + r;
      PART[((size_t)b*1024 + o)*16 + blockIdx.x] = m;
    }
  }
}

__global__ void k_reduce4(const float* __restrict__ PART,
                          const float* __restrict__ g, const float* __restrict__ be,
                          const float* __restrict__ mu, const float* __restrict__ va,
                          float* __restrict__ H4){
  int gid = blockIdx.x*256 + threadIdx.x;   // B*1024
  int o = gid & 1023;
  float M = -INFINITY;
#pragma unroll
  for (int i=0;i<16;i++) M = fmaxf(M, PART[(size_t)gid*16 + i]);
  float s = g[o]*rsqrtf(va[o]+EPSF);
  H4[gid] = lrelu(s*(M - mu[o]) + be[o]);
}

__global__ __launch_bounds__(256) void k_mlp(const float* __restrict__ H4,
      const float* __restrict__ l1w, const float* __restrict__ l1b,
      const float* __restrict__ g5, const float* __restrict__ b5,
      const float* __restrict__ m5, const float* __restrict__ v5,
      const float* __restrict__ l2w, const float* __restrict__ l2b,
      const float* __restrict__ g6, const float* __restrict__ b6,
      const float* __restrict__ m6, const float* __restrict__ v6,
      const float* __restrict__ l3w, const float* __restrict__ l3b,
      float* __restrict__ out){
  __shared__ float h[1024];
  __shared__ float h5[512];
  __shared__ float h6[256];
  int b = blockIdx.x, t = threadIdx.x;
  for (int i=t;i<1024;i+=256) h[i] = H4[b*1024+i];
  __syncthreads();
  for (int o=t;o<512;o+=256){
    float acc = l1b[o];
    for (int c=0;c<1024;c+=4){
      float4 w = *(const float4*)&l1w[(size_t)o*1024 + c];
      acc += w.x*h[c] + w.y*h[c+1] + w.z*h[c+2] + w.w*h[c+3];
    }
    float s = g5[o]*rsqrtf(v5[o]+EPSF);
    h5[o] = lrelu(s*(acc - m5[o]) + b5[o]);
  }
  __syncthreads();
  if (t < 256){
    int o = t;
    float acc = l2b[o];
    for (int c=0;c<512;c+=4){
      float4 w = *(const float4*)&l2w[(size_t)o*512 + c];
      acc += w.x*h5[c] + w.y*h5[c+1] + w.z*h5[c+2] + w.w*h5[c+3];
    }
    float s = g6[o]*rsqrtf(v6[o]+EPSF);
    h6[o] = lrelu(s*(acc - m6[o]) + b6[o]);
  }
  __syncthreads();
  if (t < 128){
    int o = t >> 6, l = t & 63;
    float p = 0.f;
#pragma unroll
    for (int j=0;j<4;j++){ int c = j*64 + l; p += l3w[o*256 + c]*h6[c]; }
    p += __shfl_xor(p, 32); p += __shfl_xor(p, 16); p += __shfl_xor(p, 8);
    p += __shfl_xor(p, 4);  p += __shfl_xor(p, 2);  p += __shfl_xor(p, 1);
    if (l == 0) out[b*2 + o] = p + l3b[o];
  }
}

extern "C" void kernel_launch(void* const* d_in, const int* in_sizes, int n_in,
                              void* d_out, int out_size, void* d_ws, size_t ws_size,
                              hipStream_t stream){
  (void)in_sizes; (void)n_in; (void)out_size; (void)ws_size;
  const float* x    = (const float*)d_in[0];
  const float* W1   = (const float*)d_in[1];
  const float* bn1g = (const float*)d_in[2];
  const float* bn1b = (const float*)d_in[3];
  const float* bn1m = (const float*)d_in[4];
  const float* bn1v = (const float*)d_in[5];
  const float* W2   = (const float*)d_in[6];
  const float* bn2g = (const float*)d_in[7];
  const float* bn2b = (const float*)d_in[8];
  const float* bn2m = (const float*)d_in[9];
  const float* bn2v = (const float*)d_in[10];
  const float* W3   = (const float*)d_in[11];
  const float* bn3g = (const float*)d_in[12];
  const float* bn3b = (const float*)d_in[13];
  const float* bn3m = (const float*)d_in[14];
  const float* bn3v = (const float*)d_in[15];
  const float* W4   = (const float*)d_in[16];
  const float* bn4g = (const float*)d_in[17];
  const float* bn4b = (const float*)d_in[18];
  const float* bn4m = (const float*)d_in[19];
  const float* bn4v = (const float*)d_in[20];
  const float* l1w  = (const float*)d_in[21];
  const float* l1b  = (const float*)d_in[22];
  const float* bn5g = (const float*)d_in[23];
  const float* bn5b = (const float*)d_in[24];
  const float* bn5m = (const float*)d_in[25];
  const float* bn5v = (const float*)d_in[26];
  const float* l2w  = (const float*)d_in[27];
  const float* l2b  = (const float*)d_in[28];
  const float* bn6g = (const float*)d_in[29];
  const float* bn6b = (const float*)d_in[30];
  const float* bn6m = (const float*)d_in[31];
  const float* bn6v = (const float*)d_in[32];
  const float* l3w  = (const float*)d_in[33];
  const float* l3b  = (const float*)d_in[34];

  float* CAT  = (float*)d_ws;                          // [8][256][2048]
  float* Yb   = CAT + (size_t)8*256*NN;                // [8][128][2048]
  float* Tb   = Yb  + (size_t)8*128*NN;                // [8][128][2048]
  float* SQ   = Tb  + (size_t)8*128*NN;                // [8][2048]
  int*   IDX  = (int*)(SQ + (size_t)8*NN);             // [8][20][2048]
  float* PART = (float*)(IDX + (size_t)8*KK*NN);       // [8][1024][16]
  float* H4   = PART + (size_t)8*1024*16;              // [8][1024]
  float* W4T  = H4 + (size_t)8*1024;                   // [256][1024]
  float* PTV  = W4T + (size_t)256*1024;                // [8][16][20][2048]
  unsigned short* PTI = (unsigned short*)(PTV + (size_t)8*16*KK*NN);  // same shape, u16

  // ---- one-time W4 transpose ----
  k_w4t<<<dim3(4,16),256,0,stream>>>(W4, W4T);
  // ---- block 1 ----
  k_prep1<<<64,256,0,stream>>>(x, W1, Yb, Tb, SQ);
  k_knn3_part<<<dim3(128,8),256,0,stream>>>(x, SQ, PTV, PTI);
  k_topk_merge16<<<64,256,0,stream>>>(PTV, PTI, IDX);
  k_edge_apply<<<dim3(16,2,8),256,0,stream>>>(Yb, Tb, IDX, bn1g, bn1b, bn1m, bn1v, CAT, 0);
  // ---- block 2 (features = CAT ch 0..63) ----
  k_sqnorm<<<64,256,0,stream>>>(CAT, SQ);
  k_knn64_part<<<dim3(128,8),256,0,stream>>>(CAT, SQ, PTV, PTI);
  k_topk_merge16<<<64,256,0,stream>>>(PTV, PTI, IDX);
  k_yt_gemm<64><<<128,256,0,stream>>>(CAT, W2, Yb, Tb);
  k_edge_apply<<<dim3(16,2,8),256,0,stream>>>(Yb, Tb, IDX, bn2g, bn2b, bn2m, bn2v, CAT, 64);
  // ---- block 3 (features = CAT ch 64..127) ----
  k_sqnorm<<<64,256,0,stream>>>(CAT + (size_t)64*NN, SQ);
  k_knn64_part<<<dim3(128,8),256,0,stream>>>(CAT + (size_t)64*NN, SQ, PTV, PTI);
  k_topk_merge16<<<64,256,0,stream>>>(PTV, PTI, IDX);
  k_yt_gemm<128><<<128,256,0,stream>>>(CAT + (size_t)64*NN, W3, Yb, Tb);
  k_edge_apply<<<dim3(16,4,8),256,0,stream>>>(Yb, Tb, IDX, bn3g, bn3b, bn3m, bn3v, CAT, 128);
  // ---- W4 + global max pool ----
  k_w4max<<<dim3(16,8,8),256,0,stream>>>(CAT, W4T, PART);
  k_reduce4<<<32,256,0,stream>>>(PART, bn4g, bn4b, bn4m, bn4v, H4);
  // ---- MLP head ----
  k_mlp<<<8,256,0,stream>>>(H4, l1w, l1b, bn5g, bn5b, bn5m, bn5v,
                            l2w, l2b, bn6g, bn6b, bn6m, bn6v, l3w, l3b, (float*)d_out);
}

// Round 9
// 1466.283 us; speedup vs baseline: 1.9836x; 1.9836x over previous
//
#include <hip/hip_runtime.h>
#include <math.h>

#define NN 2048
#define KK 20
#define EPSF 1e-5f

__device__ __forceinline__ float lrelu(float v){ return v >= 0.f ? v : 0.2f*v; }

// Sorted (descending, ties by ascending id) top-20 insert. Caller guards d > v[19].
__device__ __forceinline__ void topk20_insert(float d, int idc, float (&v)[KK], int (&id)[KK]){
#pragma unroll
  for (int j = KK-1; j >= 1; --j){
    bool cjm1 = d > v[j-1];
    bool cj   = d > v[j];
    float nv = cjm1 ? v[j-1] : (cj ? d   : v[j]);
    int   ni = cjm1 ? id[j-1] : (cj ? idc : id[j]);
    v[j] = nv; id[j] = ni;
  }
  if (d > v[0]) { v[0] = d; id[0] = idc; }
}

// ---------- stage 1 prep: sq norms + y1 = Wa1*x, t1 = (Wb1-Wa1)*x ----------
__global__ void k_prep1(const float* __restrict__ x, const float* __restrict__ W1,
                        float* __restrict__ Y, float* __restrict__ T, float* __restrict__ SQ){
  __shared__ float wa[64][3], wd[64][3];
  int t = threadIdx.x;
  if (t < 64){
#pragma unroll
    for (int c=0;c<3;c++){
      float a = W1[t*6+c], b2 = W1[t*6+3+c];
      wa[t][c] = a; wd[t][c] = b2 - a;
    }
  }
  __syncthreads();
  int gid = blockIdx.x*256 + t;
  int b = gid >> 11, n = gid & (NN-1);
  float px = x[gid*3+0], py = x[gid*3+1], pz = x[gid*3+2];
  SQ[gid] = px*px + py*py + pz*pz;
  float* yb = Y + ((size_t)b*128)*NN + n;
  float* tb = T + ((size_t)b*128)*NN + n;
#pragma unroll 8
  for (int o=0;o<64;o++){
    yb[(size_t)o*NN] = wa[o][0]*px + wa[o][1]*py + wa[o][2]*pz;
    tb[(size_t)o*NN] = wd[o][0]*px + wd[o][1]*py + wd[o][2]*pz;
  }
}

// ---------- KNN on raw xyz, candidate-split halves; each LANE writes its own partial ----------
// LDS = 2 KB (cd only). No in-kernel merge. NOTE: no min-waves launch-bounds arg (causes spills).
__global__ __launch_bounds__(256) void k_knn3_part(const float* __restrict__ x, const float* __restrict__ SQ,
                                                   float* __restrict__ PV, unsigned short* __restrict__ PI){
  __shared__ __align__(16) float cd[128*4];
  int t = threadIdx.x;
  int half = blockIdx.x & 1, nb = blockIdx.x >> 1;
  int b = blockIdx.y;
  int n_base = nb * 32;
  int cbase = half * 1024;
  int ql = t & 31, sp = t >> 5;
  int n = n_base + ql;
  int gq = b*NN + n;
  float qx = x[gq*3], qy = x[gq*3+1], qz = x[gq*3+2];
  float qs = SQ[gq];
  float v[KK]; int id[KK];
#pragma unroll
  for (int i=0;i<KK;i++){ v[i] = -INFINITY; id[i] = 0; }
  int mlo = sp * 16;
  for (int tile=0; tile<8; ++tile){
    int m0 = cbase + tile * 128;
    __syncthreads();
#pragma unroll
    for (int i=0;i<2;i++){
      int f2 = t + i*256;
      int m = f2 >> 2, ch = f2 & 3;
      int gm = b*NN + m0 + m;
      cd[f2] = (ch < 3) ? x[gm*3 + ch] : SQ[gm];
    }
    __syncthreads();
    for (int j=mlo; j<mlo+16; ++j){
      float4 c4 = *(const float4*)&cd[j*4];
      float d = 2.f*(qx*c4.x + qy*c4.y + qz*c4.z) - qs - c4.w;
      if (d > v[KK-1]) topk20_insert(d, m0 + j, v, id);
    }
  }
  // direct per-lane partial write: list id = half*8 + sp
  size_t base = ((size_t)b*16 + half*8 + sp)*KK;
#pragma unroll
  for (int r=0;r<KK;r++){
    PV[(base + r)*NN + n] = v[r];
    PI[(base + r)*NN + n] = (unsigned short)id[r];
  }
}

// ---------- squared norms of a 64-channel feature region ----------
__global__ void k_sqnorm(const float* __restrict__ X, float* __restrict__ SQ){
  int gid = blockIdx.x*256 + threadIdx.x;
  int b = gid >> 11, n = gid & (NN-1);
  const float* xb = X + (size_t)b*256*NN;
  float s = 0.f;
#pragma unroll
  for (int c=0;c<64;c++){ float vv = xb[(size_t)c*NN + n]; s += vv*vv; }
  SQ[gid] = s;
}

// ---------- KNN on 64-ch features, candidate-split halves, 64-row tiles ----------
// LDS = 64*68*4 + 64*4 = 17,664 B. Natural VGPR (~120) -> 4 waves/SIMD, no spills.
__global__ __launch_bounds__(256) void k_knn64_part(const float* __restrict__ X, const float* __restrict__ SQ,
                                                    float* __restrict__ PV, unsigned short* __restrict__ PI){
  __shared__ __align__(16) float cd[64*68];
  __shared__ float cs_[64];
  int t = threadIdx.x;
  int half = blockIdx.x & 1, nb = blockIdx.x >> 1;
  int b = blockIdx.y;
  int n_base = nb * 32;
  int cbase = half * 1024;
  int ql = t & 31, sp = t >> 5;
  int n = n_base + ql;
  const float* xb = X + (size_t)b*256*NN;
  float q[64];
#pragma unroll
  for (int c=0;c<64;c++) q[c] = xb[(size_t)c*NN + n];
  float qs = SQ[b*NN + n];
  float v[KK]; int id[KK];
#pragma unroll
  for (int i=0;i<KK;i++){ v[i]=-INFINITY; id[i]=0; }
  int jlo = sp * 8;
  for (int tile=0; tile<16; ++tile){
    int m0 = cbase + tile*64;
    __syncthreads();
#pragma unroll
    for (int i=0;i<16;i++){
      int flat = i*256 + t;
      int c = flat >> 6, m = flat & 63;
      cd[m*68 + c] = xb[(size_t)c*NN + m0 + m];
    }
    if (t < 64) cs_[t] = SQ[b*NN + m0 + t];
    __syncthreads();
    for (int j=jlo; j<jlo+8; ++j){
      const float* crow = cd + j*68;
      float d = 0.f;
#pragma unroll
      for (int c=0;c<64;c+=4){
        float4 c4 = *(const float4*)&crow[c];
        d += q[c]*c4.x + q[c+1]*c4.y + q[c+2]*c4.z + q[c+3]*c4.w;
      }
      d = 2.f*d - qs - cs_[j];
      if (d > v[KK-1]) topk20_insert(d, m0 + j, v, id);
    }
  }
  size_t base = ((size_t)b*16 + half*8 + sp)*KK;
#pragma unroll
  for (int r=0;r<KK;r++){
    PV[(base + r)*NN + n] = v[r];
    PI[(base + r)*NN + n] = (unsigned short)id[r];
  }
}

// ---------- exact 16-way merge of sorted partials (v desc, id asc) -> IDX ----------
__global__ void k_topk_merge16(const float* __restrict__ PV, const unsigned short* __restrict__ PI,
                               int* __restrict__ IDX){
  int gid = blockIdx.x*256 + threadIdx.x;   // B*NN
  int b = gid >> 11, n = gid & (NN-1);
  float hv[16]; int hi_[16]; int hp[16];
#pragma unroll
  for (int s=0;s<16;s++){
    hp[s] = 0;
    hv[s] = PV[(((size_t)b*16 + s)*KK)*NN + n];
    hi_[s] = (int)PI[(((size_t)b*16 + s)*KK)*NN + n];
  }
  for (int r=0;r<KK;r++){
    float bv = hv[0]; int bi = hi_[0]; int bs = 0;
#pragma unroll
    for (int s=1;s<16;s++){
      bool win = (hv[s] > bv) || ((hv[s] == bv) && (hi_[s] < bi));
      bv = win ? hv[s] : bv; bi = win ? hi_[s] : bi; bs = win ? s : bs;
    }
    IDX[((size_t)b*KK + r)*NN + n] = bi;
#pragma unroll
    for (int s=0;s<16;s++){
      if (s == bs){
        int np = hp[s] + 1; hp[s] = np;
        bool ok = np < KK;
        hv[s]  = ok ? PV[(((size_t)b*16 + s)*KK + np)*NN + n] : -INFINITY;
        hi_[s] = ok ? (int)PI[(((size_t)b*16 + s)*KK + np)*NN + n] : 0x7FFFFFFF;
      }
    }
  }
}

// ---------- gather-max + BN + lrelu; idx loaded once per point, reused for 16 channels ----------
__global__ __launch_bounds__(256) void k_edge_apply(const float* __restrict__ Y, const float* __restrict__ T,
                             const int* __restrict__ IDX,
                             const float* __restrict__ g, const float* __restrict__ be,
                             const float* __restrict__ mu, const float* __restrict__ va,
                             float* __restrict__ OUT, int c_off){
  int t = threadIdx.x;
  int nl = t & 127, oh = t >> 7;
  int n = blockIdx.x*128 + nl;
  int b = blockIdx.z;
  int o0 = blockIdx.y*32 + oh*16;
  int idx[KK];
#pragma unroll
  for (int k2=0;k2<KK;k2++) idx[k2] = IDX[((size_t)b*KK + k2)*NN + n];
  for (int oo=0;oo<16;oo++){
    int o = o0 + oo;
    const float* yrow = Y + ((size_t)b*128 + o)*NN;
    float M = -INFINITY;
#pragma unroll
    for (int k2=0;k2<KK;k2++) M = fmaxf(M, yrow[idx[k2]]);
    float s = g[o] * rsqrtf(va[o] + EPSF);
    float val = s*(M + T[((size_t)b*128 + o)*NN + n] - mu[o]) + be[o];
    OUT[((size_t)b*256 + c_off + o)*NN + n] = lrelu(val);
  }
}

// ---------- y = Wa*X, t = (Wb-Wa)*X  (W is (O,128): [Wa | Wb]) ----------
template<int O>
__global__ __launch_bounds__(256) void k_yt_gemm(const float* __restrict__ X, const float* __restrict__ W,
                                                 float* __restrict__ Y, float* __restrict__ T){
  __shared__ __align__(16) float wa[O][64];
  __shared__ __align__(16) float wd[O][64];
  int t = threadIdx.x;
  for (int i=t; i<O*64; i+=256){
    int o = i >> 6, c = i & 63;
    float a = W[o*128 + c];
    wa[o][c] = a;
    wd[o][c] = W[o*128 + 64 + c] - a;
  }
  __syncthreads();
  int half = t >> 7, ln = t & 127;
  int gid = blockIdx.x*128 + ln;
  int b = gid >> 11, n = gid & (NN-1);
  const float* xb = X + (size_t)b*256*NN;
  float q[64];
#pragma unroll
  for (int c=0;c<64;c++) q[c] = xb[(size_t)c*NN + n];
  int o0 = half * (O/2);
  for (int o=o0; o<o0+O/2; ++o){
    float ay=0.f, at=0.f;
#pragma unroll
    for (int c=0;c<64;c+=4){
      float4 a4 = *(const float4*)&wa[o][c];
      float4 d4 = *(const float4*)&wd[o][c];
      ay += a4.x*q[c] + a4.y*q[c+1] + a4.z*q[c+2] + a4.w*q[c+3];
      at += d4.x*q[c] + d4.y*q[c+1] + d4.z*q[c+2] + d4.w*q[c+3];
    }
    Y[((size_t)b*128 + o)*NN + n] = ay;
    T[((size_t)b*128 + o)*NN + n] = at;
  }
}

// ---------- one-time W4 transpose: W4T[c][o] = W4[o][c] ----------
__global__ __launch_bounds__(256) void k_w4t(const float* __restrict__ W4, float* __restrict__ W4T){
  __shared__ float Tt[64][65];
  int t = threadIdx.x;
  int c0 = blockIdx.x * 64, o0 = blockIdx.y * 64;
#pragma unroll
  for (int p=0;p<16;p++){
    int f = p*256 + t;
    int i = f >> 6, j = f & 63;
    Tt[i][j] = W4[(size_t)(o0+i)*256 + c0 + j];
  }
  __syncthreads();
#pragma unroll
  for (int p=0;p<16;p++){
    int f = p*256 + t;
    int i = f >> 6, j = f & 63;
    W4T[(size_t)(c0+i)*1024 + o0 + j] = Tt[j][i];
  }
}

// ---------- W4 GEMM (128x128 tile, 8x8/thread) with on-the-fly partial max over n ----------
__global__ __launch_bounds__(256) void k_w4max(const float* __restrict__ CAT, const float* __restrict__ W4T,
                                               float* __restrict__ PART){
  __shared__ __align__(16) float wt[32][132];   // [c][o]
  __shared__ __align__(16) float ct[32][132];   // [c][n]
  int t = threadIdx.x;
  int io = t >> 4, in_ = t & 15;
  int nb = blockIdx.x * 128, ob = blockIdx.y * 128, b = blockIdx.z;
  const float* catb = CAT + (size_t)b*256*NN;
  float acc[8][8];
#pragma unroll
  for (int r=0;r<8;r++)
#pragma unroll
    for (int c=0;c<8;c++) acc[r][c]=0.f;
  for (int c0=0; c0<256; c0+=32){
    __syncthreads();
#pragma unroll
    for (int p=0;p<4;p++){
      int idx = p*256 + t;            // 1024 float4 = 32c x 128o
      int cc = idx >> 5, o4 = (idx & 31) * 4;
      *(float4*)&wt[cc][o4] = *(const float4*)&W4T[(size_t)(c0+cc)*1024 + ob + o4];
    }
#pragma unroll
    for (int p=0;p<4;p++){
      int idx = p*256 + t;
      int cc = idx >> 5, n4 = (idx & 31) * 4;
      *(float4*)&ct[cc][n4] = *(const float4*)&catb[(size_t)(c0+cc)*NN + nb + n4];
    }
    __syncthreads();
#pragma unroll 4
    for (int c=0;c<32;c++){
      float4 a0 = *(const float4*)&wt[c][io*8];
      float4 a1 = *(const float4*)&wt[c][io*8+4];
      float4 b0 = *(const float4*)&ct[c][in_*8];
      float4 b1 = *(const float4*)&ct[c][in_*8+4];
      float ar[8] = {a0.x,a0.y,a0.z,a0.w,a1.x,a1.y,a1.z,a1.w};
      float br[8] = {b0.x,b0.y,b0.z,b0.w,b1.x,b1.y,b1.z,b1.w};
#pragma unroll
      for (int r=0;r<8;r++)
#pragma unroll
        for (int s=0;s<8;s++) acc[r][s] += ar[r]*br[s];
    }
  }
#pragma unroll
  for (int r=0;r<8;r++){
    float m = acc[r][0];
#pragma unroll
    for (int s=1;s<8;s++) m = fmaxf(m, acc[r][s]);
    m = fmaxf(m, __shfl_xor(m, 1));
    m = fmaxf(m, __shfl_xor(m, 2));
    m = fmaxf(m, __shfl_xor(m, 4));
    m = fmaxf(m, __shfl_xor(m, 8));
    if (in_ == 0){
      int o = ob + io*8 + r;
      PART[((size_t)b*1024 + o)*16 + blockIdx.x] = m;
    }
  }
}

__global__ void k_reduce4(const float* __restrict__ PART,
                          const float* __restrict__ g, const float* __restrict__ be,
                          const float* __restrict__ mu, const float* __restrict__ va,
                          float* __restrict__ H4){
  int gid = blockIdx.x*256 + threadIdx.x;   // B*1024
  int o = gid & 1023;
  float M = -INFINITY;
#pragma unroll
  for (int i=0;i<16;i++) M = fmaxf(M, PART[(size_t)gid*16 + i]);
  float s = g[o]*rsqrtf(va[o]+EPSF);
  H4[gid] = lrelu(s*(M - mu[o]) + be[o]);
}

__global__ __launch_bounds__(256) void k_mlp(const float* __restrict__ H4,
      const float* __restrict__ l1w, const float* __restrict__ l1b,
      const float* __restrict__ g5, const float* __restrict__ b5,
      const float* __restrict__ m5, const float* __restrict__ v5,
      const float* __restrict__ l2w, const float* __restrict__ l2b,
      const float* __restrict__ g6, const float* __restrict__ b6,
      const float* __restrict__ m6, const float* __restrict__ v6,
      const float* __restrict__ l3w, const float* __restrict__ l3b,
      float* __restrict__ out){
  __shared__ float h[1024];
  __shared__ float h5[512];
  __shared__ float h6[256];
  int b = blockIdx.x, t = threadIdx.x;
  for (int i=t;i<1024;i+=256) h[i] = H4[b*1024+i];
  __syncthreads();
  for (int o=t;o<512;o+=256){
    float acc = l1b[o];
    for (int c=0;c<1024;c+=4){
      float4 w = *(const float4*)&l1w[(size_t)o*1024 + c];
      acc += w.x*h[c] + w.y*h[c+1] + w.z*h[c+2] + w.w*h[c+3];
    }
    float s = g5[o]*rsqrtf(v5[o]+EPSF);
    h5[o] = lrelu(s*(acc - m5[o]) + b5[o]);
  }
  __syncthreads();
  if (t < 256){
    int o = t;
    float acc = l2b[o];
    for (int c=0;c<512;c+=4){
      float4 w = *(const float4*)&l2w[(size_t)o*512 + c];
      acc += w.x*h5[c] + w.y*h5[c+1] + w.z*h5[c+2] + w.w*h5[c+3];
    }
    float s = g6[o]*rsqrtf(v6[o]+EPSF);
    h6[o] = lrelu(s*(acc - m6[o]) + b6[o]);
  }
  __syncthreads();
  if (t < 128){
    int o = t >> 6, l = t & 63;
    float p = 0.f;
#pragma unroll
    for (int j=0;j<4;j++){ int c = j*64 + l; p += l3w[o*256 + c]*h6[c]; }
    p += __shfl_xor(p, 32); p += __shfl_xor(p, 16); p += __shfl_xor(p, 8);
    p += __shfl_xor(p, 4);  p += __shfl_xor(p, 2);  p += __shfl_xor(p, 1);
    if (l == 0) out[b*2 + o] = p + l3b[o];
  }
}

extern "C" void kernel_launch(void* const* d_in, const int* in_sizes, int n_in,
                              void* d_out, int out_size, void* d_ws, size_t ws_size,
                              hipStream_t stream){
  (void)in_sizes; (void)n_in; (void)out_size; (void)ws_size;
  const float* x    = (const float*)d_in[0];
  const float* W1   = (const float*)d_in[1];
  const float* bn1g = (const float*)d_in[2];
  const float* bn1b = (const float*)d_in[3];
  const float* bn1m = (const float*)d_in[4];
  const float* bn1v = (const float*)d_in[5];
  const float* W2   = (const float*)d_in[6];
  const float* bn2g = (const float*)d_in[7];
  const float* bn2b = (const float*)d_in[8];
  const float* bn2m = (const float*)d_in[9];
  const float* bn2v = (const float*)d_in[10];
  const float* W3   = (const float*)d_in[11];
  const float* bn3g = (const float*)d_in[12];
  const float* bn3b = (const float*)d_in[13];
  const float* bn3m = (const float*)d_in[14];
  const float* bn3v = (const float*)d_in[15];
  const float* W4   = (const float*)d_in[16];
  const float* bn4g = (const float*)d_in[17];
  const float* bn4b = (const float*)d_in[18];
  const float* bn4m = (const float*)d_in[19];
  const float* bn4v = (const float*)d_in[20];
  const float* l1w  = (const float*)d_in[21];
  const float* l1b  = (const float*)d_in[22];
  const float* bn5g = (const float*)d_in[23];
  const float* bn5b = (const float*)d_in[24];
  const float* bn5m = (const float*)d_in[25];
  const float* bn5v = (const float*)d_in[26];
  const float* l2w  = (const float*)d_in[27];
  const float* l2b  = (const float*)d_in[28];
  const float* bn6g = (const float*)d_in[29];
  const float* bn6b = (const float*)d_in[30];
  const float* bn6m = (const float*)d_in[31];
  const float* bn6v = (const float*)d_in[32];
  const float* l3w  = (const float*)d_in[33];
  const float* l3b  = (const float*)d_in[34];

  float* CAT  = (float*)d_ws;                          // [8][256][2048]
  float* Yb   = CAT + (size_t)8*256*NN;                // [8][128][2048]
  float* Tb   = Yb  + (size_t)8*128*NN;                // [8][128][2048]
  float* SQ   = Tb  + (size_t)8*128*NN;                // [8][2048]
  int*   IDX  = (int*)(SQ + (size_t)8*NN);             // [8][20][2048]
  float* PART = (float*)(IDX + (size_t)8*KK*NN);       // [8][1024][16]
  float* H4   = PART + (size_t)8*1024*16;              // [8][1024]
  float* W4T  = H4 + (size_t)8*1024;                   // [256][1024]
  float* PTV  = W4T + (size_t)256*1024;                // [8][16][20][2048]
  unsigned short* PTI = (unsigned short*)(PTV + (size_t)8*16*KK*NN);  // same shape, u16

  // ---- one-time W4 transpose ----
  k_w4t<<<dim3(4,16),256,0,stream>>>(W4, W4T);
  // ---- block 1 ----
  k_prep1<<<64,256,0,stream>>>(x, W1, Yb, Tb, SQ);
  k_knn3_part<<<dim3(128,8),256,0,stream>>>(x, SQ, PTV, PTI);
  k_topk_merge16<<<64,256,0,stream>>>(PTV, PTI, IDX);
  k_edge_apply<<<dim3(16,2,8),256,0,stream>>>(Yb, Tb, IDX, bn1g, bn1b, bn1m, bn1v, CAT, 0);
  // ---- block 2 (features = CAT ch 0..63) ----
  k_sqnorm<<<64,256,0,stream>>>(CAT, SQ);
  k_knn64_part<<<dim3(128,8),256,0,stream>>>(CAT, SQ, PTV, PTI);
  k_topk_merge16<<<64,256,0,stream>>>(PTV, PTI, IDX);
  k_yt_gemm<64><<<128,256,0,stream>>>(CAT, W2, Yb, Tb);
  k_edge_apply<<<dim3(16,2,8),256,0,stream>>>(Yb, Tb, IDX, bn2g, bn2b, bn2m, bn2v, CAT, 64);
  // ---- block 3 (features = CAT ch 64..127) ----
  k_sqnorm<<<64,256,0,stream>>>(CAT + (size_t)64*NN, SQ);
  k_knn64_part<<<dim3(128,8),256,0,stream>>>(CAT + (size_t)64*NN, SQ, PTV, PTI);
  k_topk_merge16<<<64,256,0,stream>>>(PTV, PTI, IDX);
  k_yt_gemm<128><<<128,256,0,stream>>>(CAT + (size_t)64*NN, W3, Yb, Tb);
  k_edge_apply<<<dim3(16,4,8),256,0,stream>>>(Yb, Tb, IDX, bn3g, bn3b, bn3m, bn3v, CAT, 128);
  // ---- W4 + global max pool ----
  k_w4max<<<dim3(16,8,8),256,0,stream>>>(CAT, W4T, PART);
  k_reduce4<<<32,256,0,stream>>>(PART, bn4g, bn4b, bn4m, bn4v, H4);
  // ---- MLP head ----
  k_mlp<<<8,256,0,stream>>>(H4, l1w, l1b, bn5g, bn5b, bn5m, bn5v,
                            l2w, l2b, bn6g, bn6b, bn6m, bn6v, l3w, l3b, (float*)d_out);
}

// Round 10
// 1424.538 us; speedup vs baseline: 2.0417x; 1.0293x over previous
//
#include <hip/hip_runtime.h>
#include <math.h>

#define NN 2048
#define KK 20
#define EPSF 1e-5f

__device__ __forceinline__ float lrelu(float v){ return v >= 0.f ? v : 0.2f*v; }

// Sorted (descending, ties by ascending id) top-20 insert. Caller guards d > v[19].
__device__ __forceinline__ void topk20_insert(float d, int idc, float (&v)[KK], int (&id)[KK]){
#pragma unroll
  for (int j = KK-1; j >= 1; --j){
    bool cjm1 = d > v[j-1];
    bool cj   = d > v[j];
    float nv = cjm1 ? v[j-1] : (cj ? d   : v[j]);
    int   ni = cjm1 ? id[j-1] : (cj ? idc : id[j]);
    v[j] = nv; id[j] = ni;
  }
  if (d > v[0]) { v[0] = d; id[0] = idc; }
}

// ---------- stage 1 prep: sq norms + y1 = Wa1*x, t1 = (Wb1-Wa1)*x ----------
__global__ void k_prep1(const float* __restrict__ x, const float* __restrict__ W1,
                        float* __restrict__ Y, float* __restrict__ T, float* __restrict__ SQ){
  __shared__ float wa[64][3], wd[64][3];
  int t = threadIdx.x;
  if (t < 64){
#pragma unroll
    for (int c=0;c<3;c++){
      float a = W1[t*6+c], b2 = W1[t*6+3+c];
      wa[t][c] = a; wd[t][c] = b2 - a;
    }
  }
  __syncthreads();
  int gid = blockIdx.x*256 + t;
  int b = gid >> 11, n = gid & (NN-1);
  float px = x[gid*3+0], py = x[gid*3+1], pz = x[gid*3+2];
  SQ[gid] = px*px + py*py + pz*pz;
  float* yb = Y + ((size_t)b*128)*NN + n;
  float* tb = T + ((size_t)b*128)*NN + n;
#pragma unroll 8
  for (int o=0;o<64;o++){
    yb[(size_t)o*NN] = wa[o][0]*px + wa[o][1]*py + wa[o][2]*pz;
    tb[(size_t)o*NN] = wd[o][0]*px + wd[o][1]*py + wd[o][2]*pz;
  }
}

// ---------- KNN on raw xyz, candidate-split halves; each LANE writes its own partial ----------
__global__ __launch_bounds__(256) void k_knn3_part(const float* __restrict__ x, const float* __restrict__ SQ,
                                                   float* __restrict__ PV, unsigned short* __restrict__ PI){
  __shared__ __align__(16) float cd[128*4];
  int t = threadIdx.x;
  int half = blockIdx.x & 1, nb = blockIdx.x >> 1;
  int b = blockIdx.y;
  int n_base = nb * 32;
  int cbase = half * 1024;
  int ql = t & 31, sp = t >> 5;
  int n = n_base + ql;
  int gq = b*NN + n;
  float qx = x[gq*3], qy = x[gq*3+1], qz = x[gq*3+2];
  float qs = SQ[gq];
  float v[KK]; int id[KK];
#pragma unroll
  for (int i=0;i<KK;i++){ v[i] = -INFINITY; id[i] = 0; }
  int mlo = sp * 16;
  for (int tile=0; tile<8; ++tile){
    int m0 = cbase + tile * 128;
    __syncthreads();
#pragma unroll
    for (int i=0;i<2;i++){
      int f2 = t + i*256;
      int m = f2 >> 2, ch = f2 & 3;
      int gm = b*NN + m0 + m;
      cd[f2] = (ch < 3) ? x[gm*3 + ch] : SQ[gm];
    }
    __syncthreads();
    for (int j=mlo; j<mlo+16; ++j){
      float4 c4 = *(const float4*)&cd[j*4];
      float d = 2.f*(qx*c4.x + qy*c4.y + qz*c4.z) - qs - c4.w;
      if (d > v[KK-1]) topk20_insert(d, m0 + j, v, id);
    }
  }
  size_t base = ((size_t)b*16 + half*8 + sp)*KK;
#pragma unroll
  for (int r=0;r<KK;r++){
    PV[(base + r)*NN + n] = v[r];
    PI[(base + r)*NN + n] = (unsigned short)id[r];
  }
}

// ---------- squared norms of a 64-channel feature region ----------
__global__ void k_sqnorm(const float* __restrict__ X, float* __restrict__ SQ){
  int gid = blockIdx.x*256 + threadIdx.x;
  int b = gid >> 11, n = gid & (NN-1);
  const float* xb = X + (size_t)b*256*NN;
  float s = 0.f;
#pragma unroll
  for (int c=0;c<64;c++){ float vv = xb[(size_t)c*NN + n]; s += vv*vv; }
  SQ[gid] = s;
}

// ---------- Gram GEMM: D[b][mlocal 0..1023][n 0..2047] = dot(x_m, x_n), m = mh*1024+mlocal ----------
// 128x128 tile, 8x8 per thread, K=64 in 2 chunks of 32 (w4max structure).
__global__ __launch_bounds__(256) void k_gram(const float* __restrict__ X, float* __restrict__ D, int mh){
  __shared__ __align__(16) float am[32][132];
  __shared__ __align__(16) float bn[32][132];
  int t = threadIdx.x;
  int io = t >> 4, in_ = t & 15;
  int nb = blockIdx.x * 128;
  int mb = blockIdx.y * 128;
  int b = blockIdx.z;
  const float* xb = X + (size_t)b*256*NN;
  int mg = mh*1024 + mb;
  float acc[8][8];
#pragma unroll
  for (int r=0;r<8;r++)
#pragma unroll
    for (int c=0;c<8;c++) acc[r][c]=0.f;
  for (int c0=0; c0<64; c0+=32){
    __syncthreads();
#pragma unroll
    for (int p=0;p<4;p++){
      int idx = p*256 + t;
      int cc = idx >> 5, m4 = (idx & 31) * 4;
      *(float4*)&am[cc][m4] = *(const float4*)&xb[(size_t)(c0+cc)*NN + mg + m4];
    }
#pragma unroll
    for (int p=0;p<4;p++){
      int idx = p*256 + t;
      int cc = idx >> 5, n4 = (idx & 31) * 4;
      *(float4*)&bn[cc][n4] = *(const float4*)&xb[(size_t)(c0+cc)*NN + nb + n4];
    }
    __syncthreads();
#pragma unroll 4
    for (int c=0;c<32;c++){
      float4 a0 = *(const float4*)&am[c][io*8];
      float4 a1 = *(const float4*)&am[c][io*8+4];
      float4 b0 = *(const float4*)&bn[c][in_*8];
      float4 b1 = *(const float4*)&bn[c][in_*8+4];
      float ar[8] = {a0.x,a0.y,a0.z,a0.w,a1.x,a1.y,a1.z,a1.w};
      float br[8] = {b0.x,b0.y,b0.z,b0.w,b1.x,b1.y,b1.z,b1.w};
#pragma unroll
      for (int r=0;r<8;r++)
#pragma unroll
        for (int s=0;s<8;s++) acc[r][s] += ar[r]*br[s];
    }
  }
#pragma unroll
  for (int r=0;r<8;r++){
    size_t row = ((size_t)b*1024 + mb + io*8 + r)*NN + nb + in_*8;
    *(float4*)&D[row]   = make_float4(acc[r][0],acc[r][1],acc[r][2],acc[r][3]);
    *(float4*)&D[row+4] = make_float4(acc[r][4],acc[r][5],acc[r][6],acc[r][7]);
  }
}

// ---------- selection over a 1024-candidate half from precomputed dots ----------
// block 256 = 32 queries x 8 splits (128 cands each). No LDS, low VGPR, batched prefetch.
// d = 2*dot - qs - cs (same order as jax/prev). Lists = mh*8 + sp (same layout as before).
__global__ __launch_bounds__(256) void k_sel1024(const float* __restrict__ D, const float* __restrict__ SQ,
                                                 int mh, float* __restrict__ PV, unsigned short* __restrict__ PI){
  int t = threadIdx.x;
  int q = t & 31, sp = t >> 5;
  int b = blockIdx.y;
  int n = blockIdx.x*32 + q;
  float qs = SQ[b*NN + n];
  const float* drow = D + ((size_t)b*1024 + sp*128)*NN + n;
  const float* sqb  = SQ + b*NN + mh*1024 + sp*128;
  int idb = mh*1024 + sp*128;
  float v[KK]; int id[KK];
#pragma unroll
  for (int i=0;i<KK;i++){ v[i]=-INFINITY; id[i]=0; }
  float dk[8];
#pragma unroll
  for (int k=0;k<8;k++) dk[k] = drow[(size_t)k*NN];
  for (int i=0;i<128;i+=8){
    float nk[8];
    if (i + 8 < 128){
#pragma unroll
      for (int k=0;k<8;k++) nk[k] = drow[(size_t)(i+8+k)*NN];
    }
#pragma unroll
    for (int k=0;k<8;k++){
      float d = 2.f*dk[k] - qs - sqb[i+k];
      if (d > v[KK-1]) topk20_insert(d, idb + i + k, v, id);
    }
#pragma unroll
    for (int k=0;k<8;k++) dk[k] = nk[k];
  }
  size_t base = ((size_t)b*16 + mh*8 + sp)*KK;
#pragma unroll
  for (int r=0;r<KK;r++){
    PV[(base + r)*NN + n] = v[r];
    PI[(base + r)*NN + n] = (unsigned short)id[r];
  }
}

// ---------- exact 16-way merge of sorted partials (v desc, id asc) -> IDX ----------
__global__ void k_topk_merge16(const float* __restrict__ PV, const unsigned short* __restrict__ PI,
                               int* __restrict__ IDX){
  int gid = blockIdx.x*256 + threadIdx.x;   // B*NN
  int b = gid >> 11, n = gid & (NN-1);
  float hv[16]; int hi_[16]; int hp[16];
#pragma unroll
  for (int s=0;s<16;s++){
    hp[s] = 0;
    hv[s] = PV[(((size_t)b*16 + s)*KK)*NN + n];
    hi_[s] = (int)PI[(((size_t)b*16 + s)*KK)*NN + n];
  }
  for (int r=0;r<KK;r++){
    float bv = hv[0]; int bi = hi_[0]; int bs = 0;
#pragma unroll
    for (int s=1;s<16;s++){
      bool win = (hv[s] > bv) || ((hv[s] == bv) && (hi_[s] < bi));
      bv = win ? hv[s] : bv; bi = win ? hi_[s] : bi; bs = win ? s : bs;
    }
    IDX[((size_t)b*KK + r)*NN + n] = bi;
#pragma unroll
    for (int s=0;s<16;s++){
      if (s == bs){
        int np = hp[s] + 1; hp[s] = np;
        bool ok = np < KK;
        hv[s]  = ok ? PV[(((size_t)b*16 + s)*KK + np)*NN + n] : -INFINITY;
        hi_[s] = ok ? (int)PI[(((size_t)b*16 + s)*KK + np)*NN + n] : 0x7FFFFFFF;
      }
    }
  }
}

// ---------- gather-max + BN + lrelu; idx loaded once per point, reused for 16 channels ----------
__global__ __launch_bounds__(256) void k_edge_apply(const float* __restrict__ Y, const float* __restrict__ T,
                             const int* __restrict__ IDX,
                             const float* __restrict__ g, const float* __restrict__ be,
                             const float* __restrict__ mu, const float* __restrict__ va,
                             float* __restrict__ OUT, int c_off){
  int t = threadIdx.x;
  int nl = t & 127, oh = t >> 7;
  int n = blockIdx.x*128 + nl;
  int b = blockIdx.z;
  int o0 = blockIdx.y*32 + oh*16;
  int idx[KK];
#pragma unroll
  for (int k2=0;k2<KK;k2++) idx[k2] = IDX[((size_t)b*KK + k2)*NN + n];
  for (int oo=0;oo<16;oo++){
    int o = o0 + oo;
    const float* yrow = Y + ((size_t)b*128 + o)*NN;
    float M = -INFINITY;
#pragma unroll
    for (int k2=0;k2<KK;k2++) M = fmaxf(M, yrow[idx[k2]]);
    float s = g[o] * rsqrtf(va[o] + EPSF);
    float val = s*(M + T[((size_t)b*128 + o)*NN + n] - mu[o]) + be[o];
    OUT[((size_t)b*256 + c_off + o)*NN + n] = lrelu(val);
  }
}

// ---------- y = Wa*X, t = (Wb-Wa)*X  (W is (O,128): [Wa | Wb]) ----------
template<int O>
__global__ __launch_bounds__(256) void k_yt_gemm(const float* __restrict__ X, const float* __restrict__ W,
                                                 float* __restrict__ Y, float* __restrict__ T){
  __shared__ __align__(16) float wa[O][64];
  __shared__ __align__(16) float wd[O][64];
  int t = threadIdx.x;
  for (int i=t; i<O*64; i+=256){
    int o = i >> 6, c = i & 63;
    float a = W[o*128 + c];
    wa[o][c] = a;
    wd[o][c] = W[o*128 + 64 + c] - a;
  }
  __syncthreads();
  int half = t >> 7, ln = t & 127;
  int gid = blockIdx.x*128 + ln;
  int b = gid >> 11, n = gid & (NN-1);
  const float* xb = X + (size_t)b*256*NN;
  float q[64];
#pragma unroll
  for (int c=0;c<64;c++) q[c] = xb[(size_t)c*NN + n];
  int o0 = half * (O/2);
  for (int o=o0; o<o0+O/2; ++o){
    float ay=0.f, at=0.f;
#pragma unroll
    for (int c=0;c<64;c+=4){
      float4 a4 = *(const float4*)&wa[o][c];
      float4 d4 = *(const float4*)&wd[o][c];
      ay += a4.x*q[c] + a4.y*q[c+1] + a4.z*q[c+2] + a4.w*q[c+3];
      at += d4.x*q[c] + d4.y*q[c+1] + d4.z*q[c+2] + d4.w*q[c+3];
    }
    Y[((size_t)b*128 + o)*NN + n] = ay;
    T[((size_t)b*128 + o)*NN + n] = at;
  }
}

// ---------- one-time W4 transpose: W4T[c][o] = W4[o][c] ----------
__global__ __launch_bounds__(256) void k_w4t(const float* __restrict__ W4, float* __restrict__ W4T){
  __shared__ float Tt[64][65];
  int t = threadIdx.x;
  int c0 = blockIdx.x * 64, o0 = blockIdx.y * 64;
#pragma unroll
  for (int p=0;p<16;p++){
    int f = p*256 + t;
    int i = f >> 6, j = f & 63;
    Tt[i][j] = W4[(size_t)(o0+i)*256 + c0 + j];
  }
  __syncthreads();
#pragma unroll
  for (int p=0;p<16;p++){
    int f = p*256 + t;
    int i = f >> 6, j = f & 63;
    W4T[(size_t)(c0+i)*1024 + o0 + j] = Tt[j][i];
  }
}

// ---------- W4 GEMM (128x128 tile, 8x8/thread) with on-the-fly partial max over n ----------
__global__ __launch_bounds__(256) void k_w4max(const float* __restrict__ CAT, const float* __restrict__ W4T,
                                               float* __restrict__ PART){
  __shared__ __align__(16) float wt[32][132];   // [c][o]
  __shared__ __align__(16) float ct[32][132];   // [c][n]
  int t = threadIdx.x;
  int io = t >> 4, in_ = t & 15;
  int nb = blockIdx.x * 128, ob = blockIdx.y * 128, b = blockIdx.z;
  const float* catb = CAT + (size_t)b*256*NN;
  float acc[8][8];
#pragma unroll
  for (int r=0;r<8;r++)
#pragma unroll
    for (int c=0;c<8;c++) acc[r][c]=0.f;
  for (int c0=0; c0<256; c0+=32){
    __syncthreads();
#pragma unroll
    for (int p=0;p<4;p++){
      int idx = p*256 + t;
      int cc = idx >> 5, o4 = (idx & 31) * 4;
      *(float4*)&wt[cc][o4] = *(const float4*)&W4T[(size_t)(c0+cc)*1024 + ob + o4];
    }
#pragma unroll
    for (int p=0;p<4;p++){
      int idx = p*256 + t;
      int cc = idx >> 5, n4 = (idx & 31) * 4;
      *(float4*)&ct[cc][n4] = *(const float4*)&catb[(size_t)(c0+cc)*NN + nb + n4];
    }
    __syncthreads();
#pragma unroll 4
    for (int c=0;c<32;c++){
      float4 a0 = *(const float4*)&wt[c][io*8];
      float4 a1 = *(const float4*)&wt[c][io*8+4];
      float4 b0 = *(const float4*)&ct[c][in_*8];
      float4 b1 = *(const float4*)&ct[c][in_*8+4];
      float ar[8] = {a0.x,a0.y,a0.z,a0.w,a1.x,a1.y,a1.z,a1.w};
      float br[8] = {b0.x,b0.y,b0.z,b0.w,b1.x,b1.y,b1.z,b1.w};
#pragma unroll
      for (int r=0;r<8;r++)
#pragma unroll
        for (int s=0;s<8;s++) acc[r][s] += ar[r]*br[s];
    }
  }
#pragma unroll
  for (int r=0;r<8;r++){
    float m = acc[r][0];
#pragma unroll
    for (int s=1;s<8;s++) m = fmaxf(m, acc[r][s]);
    m = fmaxf(m, __shfl_xor(m, 1));
    m = fmaxf(m, __shfl_xor(m, 2));
    m = fmaxf(m, __shfl_xor(m, 4));
    m = fmaxf(m, __shfl_xor(m, 8));
    if (in_ == 0){
      int o = ob + io*8 + r;
      PART[((size_t)b*1024 + o)*16 + blockIdx.x] = m;
    }
  }
}

__global__ void k_reduce4(const float* __restrict__ PART,
                          const float* __restrict__ g, const float* __restrict__ be,
                          const float* __restrict__ mu, const float* __restrict__ va,
                          float* __restrict__ H4){
  int gid = blockIdx.x*256 + threadIdx.x;   // B*1024
  int o = gid & 1023;
  float M = -INFINITY;
#pragma unroll
  for (int i=0;i<16;i++) M = fmaxf(M, PART[(size_t)gid*16 + i]);
  float s = g[o]*rsqrtf(va[o]+EPSF);
  H4[gid] = lrelu(s*(M - mu[o]) + be[o]);
}

__global__ __launch_bounds__(256) void k_mlp(const float* __restrict__ H4,
      const float* __restrict__ l1w, const float* __restrict__ l1b,
      const float* __restrict__ g5, const float* __restrict__ b5,
      const float* __restrict__ m5, const float* __restrict__ v5,
      const float* __restrict__ l2w, const float* __restrict__ l2b,
      const float* __restrict__ g6, const float* __restrict__ b6,
      const float* __restrict__ m6, const float* __restrict__ v6,
      const float* __restrict__ l3w, const float* __restrict__ l3b,
      float* __restrict__ out){
  __shared__ float h[1024];
  __shared__ float h5[512];
  __shared__ float h6[256];
  int b = blockIdx.x, t = threadIdx.x;
  for (int i=t;i<1024;i+=256) h[i] = H4[b*1024+i];
  __syncthreads();
  for (int o=t;o<512;o+=256){
    float acc = l1b[o];
    for (int c=0;c<1024;c+=4){
      float4 w = *(const float4*)&l1w[(size_t)o*1024 + c];
      acc += w.x*h[c] + w.y*h[c+1] + w.z*h[c+2] + w.w*h[c+3];
    }
    float s = g5[o]*rsqrtf(v5[o]+EPSF);
    h5[o] = lrelu(s*(acc - m5[o]) + b5[o]);
  }
  __syncthreads();
  if (t < 256){
    int o = t;
    float acc = l2b[o];
    for (int c=0;c<512;c+=4){
      float4 w = *(const float4*)&l2w[(size_t)o*512 + c];
      acc += w.x*h5[c] + w.y*h5[c+1] + w.z*h5[c+2] + w.w*h5[c+3];
    }
    float s = g6[o]*rsqrtf(v6[o]+EPSF);
    h6[o] = lrelu(s*(acc - m6[o]) + b6[o]);
  }
  __syncthreads();
  if (t < 128){
    int o = t >> 6, l = t & 63;
    float p = 0.f;
#pragma unroll
    for (int j=0;j<4;j++){ int c = j*64 + l; p += l3w[o*256 + c]*h6[c]; }
    p += __shfl_xor(p, 32); p += __shfl_xor(p, 16); p += __shfl_xor(p, 8);
    p += __shfl_xor(p, 4);  p += __shfl_xor(p, 2);  p += __shfl_xor(p, 1);
    if (l == 0) out[b*2 + o] = p + l3b[o];
  }
}

extern "C" void kernel_launch(void* const* d_in, const int* in_sizes, int n_in,
                              void* d_out, int out_size, void* d_ws, size_t ws_size,
                              hipStream_t stream){
  (void)in_sizes; (void)n_in; (void)out_size; (void)ws_size;
  const float* x    = (const float*)d_in[0];
  const float* W1   = (const float*)d_in[1];
  const float* bn1g = (const float*)d_in[2];
  const float* bn1b = (const float*)d_in[3];
  const float* bn1m = (const float*)d_in[4];
  const float* bn1v = (const float*)d_in[5];
  const float* W2   = (const float*)d_in[6];
  const float* bn2g = (const float*)d_in[7];
  const float* bn2b = (const float*)d_in[8];
  const float* bn2m = (const float*)d_in[9];
  const float* bn2v = (const float*)d_in[10];
  const float* W3   = (const float*)d_in[11];
  const float* bn3g = (const float*)d_in[12];
  const float* bn3b = (const float*)d_in[13];
  const float* bn3m = (const float*)d_in[14];
  const float* bn3v = (const float*)d_in[15];
  const float* W4   = (const float*)d_in[16];
  const float* bn4g = (const float*)d_in[17];
  const float* bn4b = (const float*)d_in[18];
  const float* bn4m = (const float*)d_in[19];
  const float* bn4v = (const float*)d_in[20];
  const float* l1w  = (const float*)d_in[21];
  const float* l1b  = (const float*)d_in[22];
  const float* bn5g = (const float*)d_in[23];
  const float* bn5b = (const float*)d_in[24];
  const float* bn5m = (const float*)d_in[25];
  const float* bn5v = (const float*)d_in[26];
  const float* l2w  = (const float*)d_in[27];
  const float* l2b  = (const float*)d_in[28];
  const float* bn6g = (const float*)d_in[29];
  const float* bn6b = (const float*)d_in[30];
  const float* bn6m = (const float*)d_in[31];
  const float* bn6v = (const float*)d_in[32];
  const float* l3w  = (const float*)d_in[33];
  const float* l3b  = (const float*)d_in[34];

  float* CAT  = (float*)d_ws;                          // [8][256][2048]   16.8 MB
  float* Yb   = CAT + (size_t)8*256*NN;                // [8][128][2048]    8.4 MB
  float* Tb   = Yb  + (size_t)8*128*NN;                // [8][128][2048]    8.4 MB
  float* SQ   = Tb  + (size_t)8*128*NN;                // [8][2048]
  int*   IDX  = (int*)(SQ + (size_t)8*NN);             // [8][20][2048]
  float* PART = (float*)(IDX + (size_t)8*KK*NN);       // [8][1024][16]
  float* H4   = PART + (size_t)8*1024*16;              // [8][1024]
  float* W4T  = H4 + (size_t)8*1024;                   // [256][1024]
  float* PTV  = W4T + (size_t)256*1024;                // [8][16][20][2048] 21.0 MB
  unsigned short* PTI = (unsigned short*)(PTV + (size_t)8*16*KK*NN);  // 10.5 MB
  float* D    = (float*)(PTI + (size_t)8*16*KK*NN);    // [8][1024][2048]  67.1 MB (half-candidate dot buffer)

  // ---- one-time W4 transpose ----
  k_w4t<<<dim3(4,16),256,0,stream>>>(W4, W4T);
  // ---- block 1 ----
  k_prep1<<<64,256,0,stream>>>(x, W1, Yb, Tb, SQ);
  k_knn3_part<<<dim3(128,8),256,0,stream>>>(x, SQ, PTV, PTI);
  k_topk_merge16<<<64,256,0,stream>>>(PTV, PTI, IDX);
  k_edge_apply<<<dim3(16,2,8),256,0,stream>>>(Yb, Tb, IDX, bn1g, bn1b, bn1m, bn1v, CAT, 0);
  // ---- block 2 (features = CAT ch 0..63) ----
  k_sqnorm<<<64,256,0,stream>>>(CAT, SQ);
  k_gram<<<dim3(16,8,8),256,0,stream>>>(CAT, D, 0);
  k_sel1024<<<dim3(64,8),256,0,stream>>>(D, SQ, 0, PTV, PTI);
  k_gram<<<dim3(16,8,8),256,0,stream>>>(CAT, D, 1);
  k_sel1024<<<dim3(64,8),256,0,stream>>>(D, SQ, 1, PTV, PTI);
  k_topk_merge16<<<64,256,0,stream>>>(PTV, PTI, IDX);
  k_yt_gemm<64><<<128,256,0,stream>>>(CAT, W2, Yb, Tb);
  k_edge_apply<<<dim3(16,2,8),256,0,stream>>>(Yb, Tb, IDX, bn2g, bn2b, bn2m, bn2v, CAT, 64);
  // ---- block 3 (features = CAT ch 64..127) ----
  k_sqnorm<<<64,256,0,stream>>>(CAT + (size_t)64*NN, SQ);
  k_gram<<<dim3(16,8,8),256,0,stream>>>(CAT + (size_t)64*NN, D, 0);
  k_sel1024<<<dim3(64,8),256,0,stream>>>(D, SQ, 0, PTV, PTI);
  k_gram<<<dim3(16,8,8),256,0,stream>>>(CAT + (size_t)64*NN, D, 1);
  k_sel1024<<<dim3(64,8),256,0,stream>>>(D, SQ, 1, PTV, PTI);
  k_topk_merge16<<<64,256,0,stream>>>(PTV, PTI, IDX);
  k_yt_gemm<128><<<128,256,0,stream>>>(CAT + (size_t)64*NN, W3, Yb, Tb);
  k_edge_apply<<<dim3(16,4,8),256,0,stream>>>(Yb, Tb, IDX, bn3g, bn3b, bn3m, bn3v, CAT, 128);
  // ---- W4 + global max pool ----
  k_w4max<<<dim3(16,8,8),256,0,stream>>>(CAT, W4T, PART);
  k_reduce4<<<32,256,0,stream>>>(PART, bn4g, bn4b, bn4m, bn4v, H4);
  // ---- MLP head ----
  k_mlp<<<8,256,0,stream>>>(H4, l1w, l1b, bn5g, bn5b, bn5m, bn5v,
                            l2w, l2b, bn6g, bn6b, bn6m, bn6v, l3w, l3b, (float*)d_out);
}